// Round 2
// baseline (244.215 us; speedup 1.0000x reference)
//
#include <hip/hip_runtime.h>

// ---------------------------------------------------------------------------
// AgglutinativeAttention: hs->QKV proj -> morpho-biased softmax attn -> out proj
// B=4 S=1024 H=1024 NH=16 HD=64.  bf16 MFMA throughout.
// R2: attn uses 32x32x16 MFMA + streaming (max-free) softmax in exp2 domain;
//     prep kernels fused into one launch (10 -> 5 dispatches).
// ---------------------------------------------------------------------------

#define SCALEc 0.125f
#define QSCALE 0.18033688011112042f   /* 0.125 * log2(e) */
#define CB0    1.0820212806667225f    /* 0.75 * log2(e) */
#define CB1    0.5193702147200268f    /* 0.36 * log2(e) */
#define VERB2  2.8853900817779268f    /* 2.0  * log2(e) */

typedef float  f32x4   __attribute__((ext_vector_type(4)));
typedef float  f32x16  __attribute__((ext_vector_type(16)));
typedef short  s16x8   __attribute__((ext_vector_type(8)));
typedef unsigned short u16x4 __attribute__((ext_vector_type(4)));
typedef unsigned short u16x8 __attribute__((ext_vector_type(8)));

#if __has_builtin(__builtin_amdgcn_exp2f)
#define EXP2F(x) __builtin_amdgcn_exp2f(x)
#else
#define EXP2F(x) exp2f(x)
#endif

__device__ __forceinline__ unsigned short f2bf(float f) {
  union { float f; unsigned u; } a; a.f = f;
  unsigned r = a.u + 0x7fffu + ((a.u >> 16) & 1u);   // RNE
  return (unsigned short)(r >> 16);
}

__device__ __forceinline__ void async16(const void* g, void* l) {
  __builtin_amdgcn_global_load_lds(
      (const __attribute__((address_space(1))) unsigned int*)g,
      (__attribute__((address_space(3))) unsigned int*)l, 16, 0, 0);
}

// ---------------- fused prep: cvt (2048) | weight-T x4 (1024) | bias (16) ---
__global__ __launch_bounds__(256) void k_prep(
    const float* __restrict__ hs, unsigned short* __restrict__ hsb,
    const float* __restrict__ Wq, const float* __restrict__ Wk,
    const float* __restrict__ Wv, const float* __restrict__ Wo,
    unsigned short* __restrict__ Wt, const int* __restrict__ mt,
    float* __restrict__ colbias, int* __restrict__ nearest) {
  __shared__ float t[64 * 68];
  int bx = blockIdx.x, tid = threadIdx.x;
  if (bx < 2048) {
    // fp32 -> bf16 convert of hidden states
    int i = (bx * 256 + tid) * 8;
    float4 v0 = *(const float4*)(hs + i);
    float4 v1 = *(const float4*)(hs + i + 4);
    u16x8 o;
    o[0] = f2bf(v0.x); o[1] = f2bf(v0.y); o[2] = f2bf(v0.z); o[3] = f2bf(v0.w);
    o[4] = f2bf(v1.x); o[5] = f2bf(v1.y); o[6] = f2bf(v1.z); o[7] = f2bf(v1.w);
    *(u16x8*)(hsb + i) = o;
  } else if (bx < 3072) {
    // weight transpose fp32 [k][n] -> bf16 [n][k]
    int w = (bx - 2048) >> 8, tt = (bx - 2048) & 255;
    const float* W = (w == 0) ? Wq : (w == 1) ? Wk : (w == 2) ? Wv : Wo;
    unsigned short* Wd = Wt + (size_t)w * 1048576;
    int n0 = (tt & 15) * 64, k0 = (tt >> 4) * 64;
    int r = tid >> 2, c0 = (tid & 3) * 16;
    const float* src = &W[(k0 + r) * 1024 + n0 + c0];
    float4 a0 = *(const float4*)(src + 0);
    float4 a1 = *(const float4*)(src + 4);
    float4 a2 = *(const float4*)(src + 8);
    float4 a3 = *(const float4*)(src + 12);
    *(float4*)&t[r * 68 + c0 + 0]  = a0;
    *(float4*)&t[r * 68 + c0 + 4]  = a1;
    *(float4*)&t[r * 68 + c0 + 8]  = a2;
    *(float4*)&t[r * 68 + c0 + 12] = a3;
    __syncthreads();
    u16x8 o0, o1;
#pragma unroll
    for (int j = 0; j < 8; j++) {
      o0[j] = f2bf(t[(c0 + j) * 68 + r]);
      o1[j] = f2bf(t[(c0 + 8 + j) * 68 + r]);
    }
    *(u16x8*)&Wd[(n0 + r) * 1024 + k0 + c0]     = o0;
    *(u16x8*)&Wd[(n0 + r) * 1024 + k0 + c0 + 8] = o1;
  } else {
    // morpho bias: nearest verb (first-min tie) + column bias (log2e-scaled)
    int i = bx - 3072;
    int b = i >> 2;
    int* sm = (int*)t;
    for (int j = tid; j < 1024; j += 256) sm[j] = mt[b * 1024 + j];
    __syncthreads();
    int q = (i & 3) * 256 + tid;
    int best = 1 << 30, bj = -1;
    for (int j = 0; j < 1024; ++j) {
      int d = (q > j) ? (q - j) : (j - q);
      int dd = (sm[j] == 2) ? d : (1 << 30);
      if (dd < best) { best = dd; bj = j; }
    }
    nearest[b * 1024 + q] = bj;
    int m = sm[q];
    colbias[b * 1024 + q] = CB0 * (m == 0) + CB1 * (m == 1);
  }
}

// ---------------- MFMA GEMM: C[r][c] = A[r][:] . Wt[c][:] + bias[c] ---------
// MODE 0: fused QKV (grid.x=24); Q scaled by QSCALE; bf16 out -> [B,NH,S,HD]
// MODE 1: out-proj (grid.x=8), fp32 out row-major [4096][1024]
template <int MODE>
__global__ __launch_bounds__(256) void k_gemm(
    const unsigned short* __restrict__ A,
    const unsigned short* __restrict__ WtBase,
    const float* __restrict__ bias0, const float* __restrict__ bias1,
    const float* __restrict__ bias2,
    unsigned short* __restrict__ outB, float* __restrict__ outF) {
  __shared__ unsigned short As[128 * 32];
  __shared__ unsigned short Bs[128 * 32];
  int tid = threadIdx.x, wid = tid >> 6, lane = tid & 63;
  int c = lane & 15, quad = lane >> 4;
  int m0 = blockIdx.y * 128;
  int wsel, n0;
  const unsigned short* Bt;
  const float* bias;
  if (MODE == 0) {
    wsel = blockIdx.x >> 3;
    n0 = (blockIdx.x & 7) * 128;
    Bt = WtBase + wsel * 1048576;
    bias = (wsel == 0) ? bias0 : ((wsel == 1) ? bias1 : bias2);
  } else {
    wsel = 0; n0 = blockIdx.x * 128; Bt = WtBase; bias = bias0;
  }
  int wm = (wid >> 1) * 64, wn = (wid & 1) * 64;
  const unsigned short* ga = A  + (m0 + wid * 32 + (lane >> 2)) * 1024 + (lane & 3) * 8;
  const unsigned short* gb = Bt + (n0 + wid * 32 + (lane >> 2)) * 1024 + (lane & 3) * 8;
  unsigned short* lA = &As[wid * 32 * 32];
  unsigned short* lB = &Bs[wid * 32 * 32];

  f32x4 acc[4][4];
#pragma unroll
  for (int i = 0; i < 4; i++)
#pragma unroll
    for (int j = 0; j < 4; j++) acc[i][j] = (f32x4){0.f, 0.f, 0.f, 0.f};

  for (int k0 = 0; k0 < 1024; k0 += 32) {
    async16(ga + k0,             lA);
    async16(ga + 16 * 1024 + k0, lA + 16 * 32);
    async16(gb + k0,             lB);
    async16(gb + 16 * 1024 + k0, lB + 16 * 32);
    __syncthreads();
    s16x8 af[4], bf[4];
#pragma unroll
    for (int i = 0; i < 4; i++) af[i] = *(const s16x8*)&As[(wm + i * 16 + c) * 32 + quad * 8];
#pragma unroll
    for (int j = 0; j < 4; j++) bf[j] = *(const s16x8*)&Bs[(wn + j * 16 + c) * 32 + quad * 8];
#pragma unroll
    for (int i = 0; i < 4; i++)
#pragma unroll
      for (int j = 0; j < 4; j++)
        acc[i][j] = __builtin_amdgcn_mfma_f32_16x16x32_bf16(af[i], bf[j], acc[i][j], 0, 0, 0);
    __syncthreads();
  }

  float sc = (MODE == 0 && wsel == 0) ? QSCALE : 1.0f;
#pragma unroll
  for (int j = 0; j < 4; j++) {
    int col = n0 + wn + j * 16 + c;
    float bv = bias[col];
    int h = col >> 6, d = col & 63;
#pragma unroll
    for (int i = 0; i < 4; i++) {
      int row = m0 + wm + i * 16 + quad * 4;
#pragma unroll
      for (int r = 0; r < 4; r++) {
        float v = (acc[i][j][r] + bv) * sc;
        int rr = row + r;
        if (MODE == 0) {
          int bb = rr >> 10, s = rr & 1023;
          outB[(size_t)wsel * 4194304 + (((bb * 16 + h) * 1024 + s) * 64) + d] = f2bf(v);
        } else {
          outF[rr * 1024 + col] = v;
        }
      }
    }
  }
}

// ---------------- V transpose: [b,h,s,d] -> [b,h,d,s] (bf16) ----------------
__global__ __launch_bounds__(256) void k_tv(const unsigned short* __restrict__ V,
                                            unsigned short* __restrict__ Vt) {
  int bh = blockIdx.y, s0 = blockIdx.x * 64;
  __shared__ unsigned short t[64][72];
  int tid = threadIdx.x;
  int r = tid >> 2, c0 = (tid & 3) * 16;
  const unsigned short* src = &V[(bh * 1024 + s0 + r) * 64 + c0];
  u16x8 a = *(const u16x8*)(src);
  u16x8 b = *(const u16x8*)(src + 8);
  *(u16x8*)&t[r][c0]     = a;
  *(u16x8*)&t[r][c0 + 8] = b;
  __syncthreads();
  u16x8 o0, o1;
#pragma unroll
  for (int j = 0; j < 8; j++) { o0[j] = t[c0 + j][r]; o1[j] = t[c0 + 8 + j][r]; }
  *(u16x8*)&Vt[(bh * 64 + r) * 1024 + s0 + c0]     = o0;
  *(u16x8*)&Vt[(bh * 64 + r) * 1024 + s0 + c0 + 8] = o1;
}

// ---------------- Flash attention, 32x32x16 MFMA, streaming softmax ---------
// Q pre-scaled by 0.125*log2e; colbias pre-scaled by log2e; exp2 domain.
// Per block: 128 q rows (4 waves x 32 q). Per chunk: 64 keys.
__global__ __launch_bounds__(256) void k_attn(
    const unsigned short* __restrict__ Q, const unsigned short* __restrict__ K,
    const unsigned short* __restrict__ Vt, const float* __restrict__ colbias,
    const int* __restrict__ nearest, unsigned short* __restrict__ AO) {
  __shared__ unsigned short Ks[64 * 72];     // [key][d]
  __shared__ unsigned short Vs[64 * 72];     // [d][key]
  __shared__ unsigned short Ps[4][32 * 72];  // per-wave [q][key]
  int tid = threadIdx.x, wid = tid >> 6, lane = tid & 63;
  int col = lane & 31, h = lane >> 5;
  int qt = blockIdx.x, bh = blockIdx.y;
  int b = bh >> 4, head = bh & 15;
  int q0 = qt * 128, wq = wid * 32;
  const unsigned short* Qg = Q  + (size_t)(bh * 1024 + q0 + wq) * 64;
  const unsigned short* Kg = K  + (size_t)bh * 1024 * 64;
  const unsigned short* Vg = Vt + (size_t)bh * 64 * 1024;

  // Q fragments (B operand): qf[t] = Q[col][16t + 8h .. +7]
  s16x8 qf[4];
#pragma unroll
  for (int t = 0; t < 4; t++)
    qf[t] = *(const s16x8*)&Qg[col * 64 + 16 * t + 8 * h];

  int nq = nearest[b * 1024 + q0 + wq + col];

  f32x16 o[2];
  o[0] = (f32x16)(0.f); o[1] = (f32x16)(0.f);
  float lrun = 0.f;

  int srow = tid >> 3, scol8 = (tid & 7) * 8;
  const float* cbB = colbias + b * 1024;

  for (int kc = 0; kc < 16; ++kc) {
#pragma unroll
    for (int it = 0; it < 2; ++it) {
      int r2 = it * 32 + srow;
      *(u16x8*)&Ks[r2 * 72 + scol8] = *(const u16x8*)&Kg[(kc * 64 + r2) * 64 + scol8];
      *(u16x8*)&Vs[r2 * 72 + scol8] = *(const u16x8*)&Vg[r2 * 1024 + kc * 64 + scol8];
    }
    __syncthreads();

    // S^T = K . Q^T : st[kt] rows = keys (kt*32 + C-row), cols = q
    f32x16 st[2];
    st[0] = (f32x16)(0.f); st[1] = (f32x16)(0.f);
#pragma unroll
    for (int t = 0; t < 4; t++) {
#pragma unroll
      for (int kt = 0; kt < 2; kt++) {
        s16x8 a = *(const s16x8*)&Ks[(kt * 32 + col) * 72 + 16 * t + 8 * h];
        st[kt] = __builtin_amdgcn_mfma_f32_32x32x16_bf16(a, qf[t], st[kt], 0, 0, 0);
      }
    }

    // bias + exp2 + partial row-sum + pack P into LDS [q][key]
#pragma unroll
    for (int kt = 0; kt < 2; kt++) {
#pragma unroll
      for (int g = 0; g < 4; g++) {
        int keybase = kc * 64 + kt * 32 + 8 * g + 4 * h;
        f32x4 cb = *(const f32x4*)&cbB[keybase];
        u16x4 pk;
#pragma unroll
        for (int rr = 0; rr < 4; rr++) {
          float x = st[kt][g * 4 + rr] + cb[rr] + ((keybase + rr == nq) ? VERB2 : 0.f);
          float e = EXP2F(x);
          lrun += e;
          pk[rr] = f2bf(e);
        }
        *(u16x4*)&Ps[wid][col * 72 + kt * 32 + 8 * g + 4 * h] = pk;
      }
    }
    __asm__ volatile("s_waitcnt lgkmcnt(0)" ::: "memory");

    // O += P . V  (A = P [q][key], B = V^T rows [d][key])
#pragma unroll
    for (int t = 0; t < 4; t++) {
      s16x8 pa = *(const s16x8*)&Ps[wid][col * 72 + 16 * t + 8 * h];
#pragma unroll
      for (int nt = 0; nt < 2; nt++) {
        s16x8 vb = *(const s16x8*)&Vs[(nt * 32 + col) * 72 + 16 * t + 8 * h];
        o[nt] = __builtin_amdgcn_mfma_f32_32x32x16_bf16(pa, vb, o[nt], 0, 0, 0);
      }
    }
    __syncthreads();
  }

  // final: combine half-partials of l, normalize, write AO [B,S,NH*HD]
  float ltot = lrun + __shfl_xor(lrun, 32, 64);
  float linv = 1.0f / ltot;
#pragma unroll
  for (int g = 0; g < 4; g++) {
#pragma unroll
    for (int rr = 0; rr < 4; rr++) {
      int qy = rr + 8 * g + 4 * h;                 // q within wave tile
      float lv = __shfl(linv, qy, 64);
      size_t row = (size_t)(b * 1024 + q0 + wq + qy);
#pragma unroll
      for (int nt = 0; nt < 2; nt++)
        AO[row * 1024 + head * 64 + nt * 32 + col] = f2bf(o[nt][g * 4 + rr] * lv);
    }
  }
}

// ---------------------------------------------------------------------------
extern "C" void kernel_launch(void* const* d_in, const int* in_sizes, int n_in,
                              void* d_out, int out_size, void* d_ws, size_t ws_size,
                              hipStream_t stream) {
  const float* hs     = (const float*)d_in[0];
  const int*   morpho = (const int*)d_in[1];
  const float* Wq = (const float*)d_in[2];
  const float* bq = (const float*)d_in[3];
  const float* Wk = (const float*)d_in[4];
  const float* bk = (const float*)d_in[5];
  const float* Wv = (const float*)d_in[6];
  const float* bv = (const float*)d_in[7];
  const float* Wo = (const float*)d_in[8];
  const float* bo = (const float*)d_in[9];
  float* out = (float*)d_out;

  char* ws = (char*)d_ws;
  unsigned short* hsb = (unsigned short*)(ws);                    // 8 MB [4096][1024]
  unsigned short* Wt  = (unsigned short*)(ws + (8u << 20));       // 8 MB [4][1024][1024]
  unsigned short* Qb  = (unsigned short*)(ws + (16u << 20));      // 8 MB [B,NH,S,HD]
  unsigned short* Vb  = (unsigned short*)(ws + (32u << 20));
  unsigned short* Kb  = (unsigned short*)(ws + (24u << 20));
  unsigned short* Vtb = (unsigned short*)(ws + (40u << 20));      // 8 MB [B,NH,HD,S]
  float* colbias      = (float*)(ws + (48u << 20));               // 16 KB
  int*   nearestp     = (int*)(ws + (48u << 20) + (16u << 10));   // 16 KB
  unsigned short* AO  = hsb;  // reuse: hs_bf16 dead after QKV GEMM

  k_prep<<<3088, 256, 0, stream>>>(hs, hsb, Wq, Wk, Wv, Wo, Wt, morpho,
                                   colbias, nearestp);
  k_gemm<0><<<dim3(24, 32), 256, 0, stream>>>(hsb, Wt, bq, bk, bv, Qb, nullptr);
  k_tv<<<dim3(16, 64), 256, 0, stream>>>(Vb, Vtb);
  k_attn<<<dim3(8, 64), 256, 0, stream>>>(Qb, Kb, Vtb, colbias, nearestp, AO);
  k_gemm<1><<<dim3(8, 32), 256, 0, stream>>>(AO, Wt + 3 * 1048576, bo, nullptr, nullptr,
                                             nullptr, out);
  (void)in_sizes; (void)n_in; (void)out_size; (void)ws_size; (void)Kb; (void)Vb;
}

// Round 3
// 231.510 us; speedup vs baseline: 1.0549x; 1.0549x over previous
//
#include <hip/hip_runtime.h>

// ---------------------------------------------------------------------------
// AgglutinativeAttention: hs->QKV proj -> morpho-biased softmax attn -> out proj
// B=4 S=1024 H=1024 NH=16 HD=64.  bf16 MFMA throughout.
// R3: attn = 16x16x32 MFMA + streaming max-free exp2 softmax + register
//     prefetch dbuf + XCD-local K/V (grid bh-major); V written pre-transposed
//     by the QKV GEMM epilogue (k_tv eliminated). 4 launches.
// ---------------------------------------------------------------------------

#define QSCALE 0.18033688011112042f   /* 0.125 * log2(e) */
#define CB0    1.0820212806667225f    /* 0.75 * log2(e) */
#define CB1    0.5193702147200268f    /* 0.36 * log2(e) */
#define VERB2  2.8853900817779268f    /* 2.0  * log2(e) */

typedef float  f32x4   __attribute__((ext_vector_type(4)));
typedef short  s16x8   __attribute__((ext_vector_type(8)));
typedef unsigned short u16x4 __attribute__((ext_vector_type(4)));
typedef unsigned short u16x8 __attribute__((ext_vector_type(8)));

#if __has_builtin(__builtin_amdgcn_exp2f)
#define EXP2F(x) __builtin_amdgcn_exp2f(x)
#else
#define EXP2F(x) exp2f(x)
#endif

__device__ __forceinline__ unsigned short f2bf(float f) {
  union { float f; unsigned u; } a; a.f = f;
  unsigned r = a.u + 0x7fffu + ((a.u >> 16) & 1u);   // RNE
  return (unsigned short)(r >> 16);
}

__device__ __forceinline__ void async16(const void* g, void* l) {
  __builtin_amdgcn_global_load_lds(
      (const __attribute__((address_space(1))) unsigned int*)g,
      (__attribute__((address_space(3))) unsigned int*)l, 16, 0, 0);
}

// ---------------- fused prep: cvt (2048) | weight-T x4 (1024) | bias (16) ---
__global__ __launch_bounds__(256) void k_prep(
    const float* __restrict__ hs, unsigned short* __restrict__ hsb,
    const float* __restrict__ Wq, const float* __restrict__ Wk,
    const float* __restrict__ Wv, const float* __restrict__ Wo,
    unsigned short* __restrict__ Wt, const int* __restrict__ mt,
    float* __restrict__ colbias, int* __restrict__ nearest) {
  __shared__ float t[64 * 68];
  int bx = blockIdx.x, tid = threadIdx.x;
  if (bx < 2048) {
    int i = (bx * 256 + tid) * 8;
    float4 v0 = *(const float4*)(hs + i);
    float4 v1 = *(const float4*)(hs + i + 4);
    u16x8 o;
    o[0] = f2bf(v0.x); o[1] = f2bf(v0.y); o[2] = f2bf(v0.z); o[3] = f2bf(v0.w);
    o[4] = f2bf(v1.x); o[5] = f2bf(v1.y); o[6] = f2bf(v1.z); o[7] = f2bf(v1.w);
    *(u16x8*)(hsb + i) = o;
  } else if (bx < 3072) {
    int w = (bx - 2048) >> 8, tt = (bx - 2048) & 255;
    const float* W = (w == 0) ? Wq : (w == 1) ? Wk : (w == 2) ? Wv : Wo;
    unsigned short* Wd = Wt + (size_t)w * 1048576;
    int n0 = (tt & 15) * 64, k0 = (tt >> 4) * 64;
    int r = tid >> 2, c0 = (tid & 3) * 16;
    const float* src = &W[(k0 + r) * 1024 + n0 + c0];
    float4 a0 = *(const float4*)(src + 0);
    float4 a1 = *(const float4*)(src + 4);
    float4 a2 = *(const float4*)(src + 8);
    float4 a3 = *(const float4*)(src + 12);
    *(float4*)&t[r * 68 + c0 + 0]  = a0;
    *(float4*)&t[r * 68 + c0 + 4]  = a1;
    *(float4*)&t[r * 68 + c0 + 8]  = a2;
    *(float4*)&t[r * 68 + c0 + 12] = a3;
    __syncthreads();
    u16x8 o0, o1;
#pragma unroll
    for (int j = 0; j < 8; j++) {
      o0[j] = f2bf(t[(c0 + j) * 68 + r]);
      o1[j] = f2bf(t[(c0 + 8 + j) * 68 + r]);
    }
    *(u16x8*)&Wd[(n0 + r) * 1024 + k0 + c0]     = o0;
    *(u16x8*)&Wd[(n0 + r) * 1024 + k0 + c0 + 8] = o1;
  } else {
    int i = bx - 3072;
    int b = i >> 2;
    int* sm = (int*)t;
    for (int j = tid; j < 1024; j += 256) sm[j] = mt[b * 1024 + j];
    __syncthreads();
    int q = (i & 3) * 256 + tid;
    int best = 1 << 30, bj = -1;
    for (int j = 0; j < 1024; ++j) {
      int d = (q > j) ? (q - j) : (j - q);
      int dd = (sm[j] == 2) ? d : (1 << 30);
      if (dd < best) { best = dd; bj = j; }
    }
    nearest[b * 1024 + q] = bj;
    int m = sm[q];
    colbias[b * 1024 + q] = CB0 * (m == 0) + CB1 * (m == 1);
  }
}

// ---------------- MFMA GEMM: C[r][c] = A[r][:] . Wt[c][:] + bias[c] ---------
// MODE 0: fused QKV (grid.x=24); Q scaled by QSCALE; Q/K -> [B,NH,S,HD] bf16;
//         V -> transposed [B,NH,HD,S] bf16 (packed 8B stores).
// MODE 1: out-proj (grid.x=8), fp32 out row-major [4096][1024]
template <int MODE>
__global__ __launch_bounds__(256) void k_gemm(
    const unsigned short* __restrict__ A,
    const unsigned short* __restrict__ WtBase,
    const float* __restrict__ bias0, const float* __restrict__ bias1,
    const float* __restrict__ bias2,
    unsigned short* __restrict__ outB, unsigned short* __restrict__ outV,
    float* __restrict__ outF) {
  __shared__ unsigned short As[128 * 32];
  __shared__ unsigned short Bs[128 * 32];
  int tid = threadIdx.x, wid = tid >> 6, lane = tid & 63;
  int c = lane & 15, quad = lane >> 4;
  int m0 = blockIdx.y * 128;
  int wsel, n0;
  const unsigned short* Bt;
  const float* bias;
  if (MODE == 0) {
    wsel = blockIdx.x >> 3;
    n0 = (blockIdx.x & 7) * 128;
    Bt = WtBase + wsel * 1048576;
    bias = (wsel == 0) ? bias0 : ((wsel == 1) ? bias1 : bias2);
  } else {
    wsel = 0; n0 = blockIdx.x * 128; Bt = WtBase; bias = bias0;
  }
  int wm = (wid >> 1) * 64, wn = (wid & 1) * 64;
  const unsigned short* ga = A  + (m0 + wid * 32 + (lane >> 2)) * 1024 + (lane & 3) * 8;
  const unsigned short* gb = Bt + (n0 + wid * 32 + (lane >> 2)) * 1024 + (lane & 3) * 8;
  unsigned short* lA = &As[wid * 32 * 32];
  unsigned short* lB = &Bs[wid * 32 * 32];

  f32x4 acc[4][4];
#pragma unroll
  for (int i = 0; i < 4; i++)
#pragma unroll
    for (int j = 0; j < 4; j++) acc[i][j] = (f32x4){0.f, 0.f, 0.f, 0.f};

  for (int k0 = 0; k0 < 1024; k0 += 32) {
    async16(ga + k0,             lA);
    async16(ga + 16 * 1024 + k0, lA + 16 * 32);
    async16(gb + k0,             lB);
    async16(gb + 16 * 1024 + k0, lB + 16 * 32);
    __syncthreads();
    s16x8 af[4], bf[4];
#pragma unroll
    for (int i = 0; i < 4; i++) af[i] = *(const s16x8*)&As[(wm + i * 16 + c) * 32 + quad * 8];
#pragma unroll
    for (int j = 0; j < 4; j++) bf[j] = *(const s16x8*)&Bs[(wn + j * 16 + c) * 32 + quad * 8];
#pragma unroll
    for (int i = 0; i < 4; i++)
#pragma unroll
      for (int j = 0; j < 4; j++)
        acc[i][j] = __builtin_amdgcn_mfma_f32_16x16x32_bf16(af[i], bf[j], acc[i][j], 0, 0, 0);
    __syncthreads();
  }

  if (MODE == 1) {
#pragma unroll
    for (int j = 0; j < 4; j++) {
      int col = n0 + wn + j * 16 + c;
      float bv = bias[col];
#pragma unroll
      for (int i = 0; i < 4; i++) {
        int row = m0 + wm + i * 16 + quad * 4;
#pragma unroll
        for (int r = 0; r < 4; r++) outF[(row + r) * 1024 + col] = acc[i][j][r] + bv;
      }
    }
  } else if (wsel == 2) {
    // V: write transposed [b,h,d,s]; r-consecutive s -> packed 8B stores
#pragma unroll
    for (int j = 0; j < 4; j++) {
      int col = n0 + wn + j * 16 + c;
      float bv = bias[col];
      int h = col >> 6, d = col & 63;
#pragma unroll
      for (int i = 0; i < 4; i++) {
        int row = m0 + wm + i * 16 + quad * 4;
        int bb = row >> 10, s = row & 1023;
        u16x4 pk;
#pragma unroll
        for (int r = 0; r < 4; r++) pk[r] = f2bf(acc[i][j][r] + bv);
        *(u16x4*)&outV[(size_t)(((bb * 16 + h) * 64 + d)) * 1024 + s] = pk;
      }
    }
  } else {
    float sc = (wsel == 0) ? QSCALE : 1.0f;
#pragma unroll
    for (int j = 0; j < 4; j++) {
      int col = n0 + wn + j * 16 + c;
      float bv = bias[col];
      int h = col >> 6, d = col & 63;
#pragma unroll
      for (int i = 0; i < 4; i++) {
        int row = m0 + wm + i * 16 + quad * 4;
#pragma unroll
        for (int r = 0; r < 4; r++) {
          int rr = row + r;
          int bb = rr >> 10, s = rr & 1023;
          outB[(size_t)wsel * 4194304 + (((bb * 16 + h) * 1024 + s) * 64) + d] =
              f2bf((acc[i][j][r] + bv) * sc);
        }
      }
    }
  }
}

// ---------------- Flash attention, 16x16x32 MFMA, streaming softmax ---------
// grid (bh=64, qt=8): blocks sharing bh land on one XCD (linear%8 == bh%8),
// K+V per XCD = 2 MB -> L2-resident re-reads. Register-prefetch dbuf: chunk
// kc+1 loads issue right after staging barrier, overlap chunk kc compute.
__global__ __launch_bounds__(256) void k_attn(
    const unsigned short* __restrict__ Q, const unsigned short* __restrict__ K,
    const unsigned short* __restrict__ Vt, const float* __restrict__ colbias,
    const int* __restrict__ nearest, unsigned short* __restrict__ AO) {
  __shared__ unsigned short Ks[64 * 72];     // [key][d]
  __shared__ unsigned short Vs[64 * 72];     // [d][key]
  __shared__ unsigned short Ps[4][32 * 72];  // per-wave [q][key]
  __shared__ float Cb[1024];
  int tid = threadIdx.x, wid = tid >> 6, lane = tid & 63;
  int c = lane & 15, quad = lane >> 4;
  int bh = blockIdx.x, qt = blockIdx.y;
  int b = bh >> 4, head = bh & 15;
  int q0 = qt * 128, wq = wid * 32;
  const unsigned short* Qg = Q  + (size_t)(bh * 1024 + q0 + wq) * 64;
  const unsigned short* Kg = K  + (size_t)bh * 1024 * 64;
  const unsigned short* Vg = Vt + (size_t)bh * 64 * 1024;

  // colbias row -> LDS (read 16x per chunk otherwise)
  *(float4*)&Cb[tid * 4] = *(const float4*)&colbias[b * 1024 + tid * 4];

  // Q fragments (B operand): n=q=c, k=quad*8+j within 32-chunk ks
  s16x8 qf[2][2];
#pragma unroll
  for (int nt = 0; nt < 2; nt++)
#pragma unroll
    for (int ks = 0; ks < 2; ks++)
      qf[nt][ks] = *(const s16x8*)&Qg[(nt * 16 + c) * 64 + ks * 32 + quad * 8];

  int nq[2];
  nq[0] = nearest[b * 1024 + q0 + wq + c];
  nq[1] = nearest[b * 1024 + q0 + wq + 16 + c];

  f32x4 o[2][4];
#pragma unroll
  for (int i = 0; i < 2; i++)
#pragma unroll
    for (int j = 0; j < 4; j++) o[i][j] = (f32x4){0.f, 0.f, 0.f, 0.f};
  float lrun[2] = {0.f, 0.f};

  int srow = tid >> 3, scol8 = (tid & 7) * 8;

  // prefetch chunk 0 into registers
  u16x8 kr[2], vr[2];
#pragma unroll
  for (int it = 0; it < 2; ++it) {
    int r2 = it * 32 + srow;
    kr[it] = *(const u16x8*)&Kg[r2 * 64 + scol8];
    vr[it] = *(const u16x8*)&Vg[r2 * 1024 + scol8];
  }
  __syncthreads();   // Cb visible before first use

  for (int kc = 0; kc < 16; ++kc) {
#pragma unroll
    for (int it = 0; it < 2; ++it) {
      int r2 = it * 32 + srow;
      *(u16x8*)&Ks[r2 * 72 + scol8] = kr[it];
      *(u16x8*)&Vs[r2 * 72 + scol8] = vr[it];
    }
    __syncthreads();
    if (kc < 15) {
#pragma unroll
      for (int it = 0; it < 2; ++it) {
        int r2 = it * 32 + srow;
        kr[it] = *(const u16x8*)&Kg[((kc + 1) * 64 + r2) * 64 + scol8];
        vr[it] = *(const u16x8*)&Vg[r2 * 1024 + (kc + 1) * 64 + scol8];
      }
    }

    // S^T = K . Q^T : st[mt][nt] (key = mt*16+quad*4+r, q = nt*16+c)
    f32x4 st[4][2];
#pragma unroll
    for (int mt = 0; mt < 4; mt++)
#pragma unroll
      for (int nt = 0; nt < 2; nt++) st[mt][nt] = (f32x4){0.f, 0.f, 0.f, 0.f};
#pragma unroll
    for (int mt = 0; mt < 4; mt++)
#pragma unroll
      for (int ks = 0; ks < 2; ks++) {
        s16x8 a = *(const s16x8*)&Ks[(mt * 16 + c) * 72 + ks * 32 + quad * 8];
#pragma unroll
        for (int nt = 0; nt < 2; nt++)
          st[mt][nt] = __builtin_amdgcn_mfma_f32_16x16x32_bf16(a, qf[nt][ks], st[mt][nt], 0, 0, 0);
      }

    // bias + exp2 + partial row-sum + pack P -> LDS [q][key]
#pragma unroll
    for (int mt = 0; mt < 4; mt++) {
      f32x4 cb = *(const f32x4*)&Cb[kc * 64 + mt * 16 + quad * 4];
#pragma unroll
      for (int nt = 0; nt < 2; nt++) {
        u16x4 pk;
#pragma unroll
        for (int r = 0; r < 4; r++) {
          int keyg = kc * 64 + mt * 16 + quad * 4 + r;
          float x = st[mt][nt][r] + cb[r] + ((keyg == nq[nt]) ? VERB2 : 0.f);
          float e = EXP2F(x);
          lrun[nt] += e;
          pk[r] = f2bf(e);
        }
        *(u16x4*)&Ps[wid][(nt * 16 + c) * 72 + mt * 16 + quad * 4] = pk;
      }
    }
    __asm__ volatile("s_waitcnt lgkmcnt(0)" ::: "memory");

    // O += P . V
#pragma unroll
    for (int ks = 0; ks < 2; ks++) {
      s16x8 pa[2];
#pragma unroll
      for (int mtq = 0; mtq < 2; mtq++)
        pa[mtq] = *(const s16x8*)&Ps[wid][(mtq * 16 + c) * 72 + ks * 32 + quad * 8];
#pragma unroll
      for (int ntd = 0; ntd < 4; ntd++) {
        s16x8 vb = *(const s16x8*)&Vs[(ntd * 16 + c) * 72 + ks * 32 + quad * 8];
#pragma unroll
        for (int mtq = 0; mtq < 2; mtq++)
          o[mtq][ntd] = __builtin_amdgcn_mfma_f32_16x16x32_bf16(pa[mtq], vb, o[mtq][ntd], 0, 0, 0);
      }
    }
    __syncthreads();
  }

  // reduce row-sums across quads (keys were split quad-wise), normalize, write
#pragma unroll
  for (int nt = 0; nt < 2; nt++) {
    lrun[nt] += __shfl_xor(lrun[nt], 16, 64);
    lrun[nt] += __shfl_xor(lrun[nt], 32, 64);
  }
  float linv[2] = {1.0f / lrun[0], 1.0f / lrun[1]};
#pragma unroll
  for (int mtq = 0; mtq < 2; mtq++)
#pragma unroll
    for (int r = 0; r < 4; r++) {
      float lq = __shfl(linv[mtq], quad * 4 + r, 64);
      size_t row = (size_t)(b * 1024 + q0 + wq + mtq * 16 + quad * 4 + r);
#pragma unroll
      for (int ntd = 0; ntd < 4; ntd++)
        AO[row * 1024 + head * 64 + ntd * 16 + c] = f2bf(o[mtq][ntd][r] * lq);
    }
}

// ---------------------------------------------------------------------------
extern "C" void kernel_launch(void* const* d_in, const int* in_sizes, int n_in,
                              void* d_out, int out_size, void* d_ws, size_t ws_size,
                              hipStream_t stream) {
  const float* hs     = (const float*)d_in[0];
  const int*   morpho = (const int*)d_in[1];
  const float* Wq = (const float*)d_in[2];
  const float* bq = (const float*)d_in[3];
  const float* Wk = (const float*)d_in[4];
  const float* bk = (const float*)d_in[5];
  const float* Wv = (const float*)d_in[6];
  const float* bv = (const float*)d_in[7];
  const float* Wo = (const float*)d_in[8];
  const float* bo = (const float*)d_in[9];
  float* out = (float*)d_out;

  char* ws = (char*)d_ws;
  unsigned short* hsb = (unsigned short*)(ws);                    // 8 MB [4096][1024]
  unsigned short* Wt  = (unsigned short*)(ws + (8u << 20));       // 8 MB [4][1024][1024]
  unsigned short* Qb  = (unsigned short*)(ws + (16u << 20));      // Q at +16MB, K at +24MB
  unsigned short* Kb  = (unsigned short*)(ws + (24u << 20));
  unsigned short* Vtb = (unsigned short*)(ws + (40u << 20));      // 8 MB [B,NH,HD,S]
  float* colbias      = (float*)(ws + (48u << 20));               // 16 KB
  int*   nearestp     = (int*)(ws + (48u << 20) + (16u << 10));   // 16 KB
  unsigned short* AO  = hsb;  // reuse: hs_bf16 dead after QKV GEMM

  k_prep<<<3088, 256, 0, stream>>>(hs, hsb, Wq, Wk, Wv, Wo, Wt, morpho,
                                   colbias, nearestp);
  k_gemm<0><<<dim3(24, 32), 256, 0, stream>>>(hsb, Wt, bq, bk, bv, Qb, Vtb, nullptr);
  k_attn<<<dim3(64, 8), 256, 0, stream>>>(Qb, Kb, Vtb, colbias, nearestp, AO);
  k_gemm<1><<<dim3(8, 32), 256, 0, stream>>>(AO, Wt + 3 * 1048576, bo, nullptr, nullptr,
                                             nullptr, nullptr, out);
  (void)in_sizes; (void)n_in; (void)out_size; (void)ws_size; (void)Kb;
}

// Round 4
// 229.760 us; speedup vs baseline: 1.0629x; 1.0076x over previous
//
#include <hip/hip_runtime.h>

// ---------------------------------------------------------------------------
// AgglutinativeAttention: hs->QKV proj -> morpho-biased softmax attn -> out proj
// B=4 S=1024 H=1024 NH=16 HD=64.  bf16 MFMA throughout.
// R4: swapped-operand MFMA epilogues (C transposed -> packed u16x4/float4
//     stores instead of scattered scalar stores) in both GEMMs and attn's AO
//     write; XCD-locality swizzles for both GEMM grids.
// ---------------------------------------------------------------------------

#define QSCALE 0.18033688011112042f   /* 0.125 * log2(e) */
#define CB0    1.0820212806667225f    /* 0.75 * log2(e) */
#define CB1    0.5193702147200268f    /* 0.36 * log2(e) */
#define VERB2  2.8853900817779268f    /* 2.0  * log2(e) */

typedef float  f32x4   __attribute__((ext_vector_type(4)));
typedef short  s16x8   __attribute__((ext_vector_type(8)));
typedef unsigned short u16x4 __attribute__((ext_vector_type(4)));
typedef unsigned short u16x8 __attribute__((ext_vector_type(8)));

#if __has_builtin(__builtin_amdgcn_exp2f)
#define EXP2F(x) __builtin_amdgcn_exp2f(x)
#else
#define EXP2F(x) exp2f(x)
#endif

__device__ __forceinline__ unsigned short f2bf(float f) {
  union { float f; unsigned u; } a; a.f = f;
  unsigned r = a.u + 0x7fffu + ((a.u >> 16) & 1u);   // RNE
  return (unsigned short)(r >> 16);
}

__device__ __forceinline__ void async16(const void* g, void* l) {
  __builtin_amdgcn_global_load_lds(
      (const __attribute__((address_space(1))) unsigned int*)g,
      (__attribute__((address_space(3))) unsigned int*)l, 16, 0, 0);
}

// ---------------- fused prep: cvt (2048) | weight-T x4 (1024) | bias (16) ---
__global__ __launch_bounds__(256) void k_prep(
    const float* __restrict__ hs, unsigned short* __restrict__ hsb,
    const float* __restrict__ Wq, const float* __restrict__ Wk,
    const float* __restrict__ Wv, const float* __restrict__ Wo,
    unsigned short* __restrict__ Wt, const int* __restrict__ mt,
    float* __restrict__ colbias, int* __restrict__ nearest) {
  __shared__ float t[64 * 68];
  int bx = blockIdx.x, tid = threadIdx.x;
  if (bx < 2048) {
    int i = (bx * 256 + tid) * 8;
    float4 v0 = *(const float4*)(hs + i);
    float4 v1 = *(const float4*)(hs + i + 4);
    u16x8 o;
    o[0] = f2bf(v0.x); o[1] = f2bf(v0.y); o[2] = f2bf(v0.z); o[3] = f2bf(v0.w);
    o[4] = f2bf(v1.x); o[5] = f2bf(v1.y); o[6] = f2bf(v1.z); o[7] = f2bf(v1.w);
    *(u16x8*)(hsb + i) = o;
  } else if (bx < 3072) {
    int w = (bx - 2048) >> 8, tt = (bx - 2048) & 255;
    const float* W = (w == 0) ? Wq : (w == 1) ? Wk : (w == 2) ? Wv : Wo;
    unsigned short* Wd = Wt + (size_t)w * 1048576;
    int n0 = (tt & 15) * 64, k0 = (tt >> 4) * 64;
    int r = tid >> 2, c0 = (tid & 3) * 16;
    const float* src = &W[(k0 + r) * 1024 + n0 + c0];
    float4 a0 = *(const float4*)(src + 0);
    float4 a1 = *(const float4*)(src + 4);
    float4 a2 = *(const float4*)(src + 8);
    float4 a3 = *(const float4*)(src + 12);
    *(float4*)&t[r * 68 + c0 + 0]  = a0;
    *(float4*)&t[r * 68 + c0 + 4]  = a1;
    *(float4*)&t[r * 68 + c0 + 8]  = a2;
    *(float4*)&t[r * 68 + c0 + 12] = a3;
    __syncthreads();
    u16x8 o0, o1;
#pragma unroll
    for (int j = 0; j < 8; j++) {
      o0[j] = f2bf(t[(c0 + j) * 68 + r]);
      o1[j] = f2bf(t[(c0 + 8 + j) * 68 + r]);
    }
    *(u16x8*)&Wd[(n0 + r) * 1024 + k0 + c0]     = o0;
    *(u16x8*)&Wd[(n0 + r) * 1024 + k0 + c0 + 8] = o1;
  } else {
    int i = bx - 3072;
    int b = i >> 2;
    int* sm = (int*)t;
    for (int j = tid; j < 1024; j += 256) sm[j] = mt[b * 1024 + j];
    __syncthreads();
    int q = (i & 3) * 256 + tid;
    int best = 1 << 30, bj = -1;
    for (int j = 0; j < 1024; ++j) {
      int d = (q > j) ? (q - j) : (j - q);
      int dd = (sm[j] == 2) ? d : (1 << 30);
      if (dd < best) { best = dd; bj = j; }
    }
    nearest[b * 1024 + q] = bj;
    int m = sm[q];
    colbias[b * 1024 + q] = CB0 * (m == 0) + CB1 * (m == 1);
  }
}

// ---------------- MFMA GEMM ------------------------------------------------
// MODE 0: fused QKV (grid 24x32); Q/K use SWAPPED operands (C rows=features,
//         cols=tokens) -> packed u16x4 stores into [B,NH,S,HD]; V uses normal
//         order -> packed u16x4 stores into transposed [B,NH,HD,S].
// MODE 1: out-proj (grid 8x32); swapped -> float4 stores, fp32 [4096][1024].
// Both grids XCD-swizzled: blocks with equal (linear%8) share an m-range.
template <int MODE>
__global__ __launch_bounds__(256) void k_gemm(
    const unsigned short* __restrict__ A,
    const unsigned short* __restrict__ WtBase,
    const float* __restrict__ bias0, const float* __restrict__ bias1,
    const float* __restrict__ bias2,
    unsigned short* __restrict__ outB, unsigned short* __restrict__ outV,
    float* __restrict__ outF) {
  __shared__ unsigned short As[128 * 32];
  __shared__ unsigned short Bs[128 * 32];
  int tid = threadIdx.x, wid = tid >> 6, lane = tid & 63;
  int c = lane & 15, quad = lane >> 4;
  int m0, wsel, n0;
  const unsigned short* Bt;
  const float* bias;
  if (MODE == 0) {
    // 768 blocks: xcd = lin&7 -> (m-group of 8, x-group of 12): A 2MB + W 3MB /XCD
    int lin = blockIdx.x + 24 * blockIdx.y;
    int xcd = lin & 7, idx = lin >> 3;
    m0 = (((xcd >> 1) << 3) + (idx & 7)) * 128;
    int xt = (xcd & 1) * 12 + (idx >> 3);
    wsel = xt >> 3;
    n0 = (xt & 7) * 128;
    Bt = WtBase + wsel * 1048576;
    bias = (wsel == 0) ? bias0 : ((wsel == 1) ? bias1 : bias2);
  } else {
    // 256 blocks: xcd = lin&7 -> (m-group of 4, all n): A 1MB + W 2MB /XCD
    int lin = blockIdx.x + 8 * blockIdx.y;
    int xcd = lin & 7, idx = lin >> 3;
    m0 = ((xcd << 2) + (idx & 3)) * 128;
    n0 = (idx >> 2) * 128;
    wsel = 0; Bt = WtBase; bias = bias0;
  }
  int wm = (wid >> 1) * 64, wn = (wid & 1) * 64;
  const unsigned short* ga = A  + (m0 + wid * 32 + (lane >> 2)) * 1024 + (lane & 3) * 8;
  const unsigned short* gb = Bt + (n0 + wid * 32 + (lane >> 2)) * 1024 + (lane & 3) * 8;
  unsigned short* lA = &As[wid * 32 * 32];
  unsigned short* lB = &Bs[wid * 32 * 32];

  f32x4 acc[4][4];
#pragma unroll
  for (int i = 0; i < 4; i++)
#pragma unroll
    for (int j = 0; j < 4; j++) acc[i][j] = (f32x4){0.f, 0.f, 0.f, 0.f};

  bool sw = (MODE == 1) || (wsel != 2);   // swapped-operand mode (wave-uniform)

  for (int k0 = 0; k0 < 1024; k0 += 32) {
    async16(ga + k0,             lA);
    async16(ga + 16 * 1024 + k0, lA + 16 * 32);
    async16(gb + k0,             lB);
    async16(gb + 16 * 1024 + k0, lB + 16 * 32);
    __syncthreads();
    s16x8 af[4], bf[4];
#pragma unroll
    for (int i = 0; i < 4; i++) af[i] = *(const s16x8*)&As[(wm + i * 16 + c) * 32 + quad * 8];
#pragma unroll
    for (int j = 0; j < 4; j++) bf[j] = *(const s16x8*)&Bs[(wn + j * 16 + c) * 32 + quad * 8];
    if (sw) {
#pragma unroll
      for (int i = 0; i < 4; i++)
#pragma unroll
        for (int j = 0; j < 4; j++)
          acc[i][j] = __builtin_amdgcn_mfma_f32_16x16x32_bf16(bf[j], af[i], acc[i][j], 0, 0, 0);
    } else {
#pragma unroll
      for (int i = 0; i < 4; i++)
#pragma unroll
        for (int j = 0; j < 4; j++)
          acc[i][j] = __builtin_amdgcn_mfma_f32_16x16x32_bf16(af[i], bf[j], acc[i][j], 0, 0, 0);
    }
    __syncthreads();
  }

  if (MODE == 1) {
    // swapped: row=feature (4-contig), col=token -> float4 stores
#pragma unroll
    for (int j = 0; j < 4; j++) {
      int colb = n0 + wn + j * 16 + quad * 4;
      f32x4 bvv = *(const f32x4*)&bias[colb];
#pragma unroll
      for (int i = 0; i < 4; i++) {
        int s_tok = m0 + wm + i * 16 + c;
        f32x4 v = acc[i][j] + bvv;
        *(f32x4*)&outF[(size_t)s_tok * 1024 + colb] = v;
      }
    }
  } else if (wsel == 2) {
    // V normal order: row=token (4-contig) -> u16x4 into [b,h,d,s]
#pragma unroll
    for (int j = 0; j < 4; j++) {
      int col = n0 + wn + j * 16 + c;
      float bv = bias[col];
      int h = col >> 6, d = col & 63;
#pragma unroll
      for (int i = 0; i < 4; i++) {
        int row = m0 + wm + i * 16 + quad * 4;
        int bb = row >> 10, s = row & 1023;
        u16x4 pk;
#pragma unroll
        for (int r = 0; r < 4; r++) pk[r] = f2bf(acc[i][j][r] + bv);
        *(u16x4*)&outV[(size_t)(((bb * 16 + h) * 64 + d)) * 1024 + s] = pk;
      }
    }
  } else {
    // Q/K swapped: row=feature (4-contig), col=token -> u16x4 into [b,h,s,d]
    float sc = (wsel == 0) ? QSCALE : 1.0f;
#pragma unroll
    for (int j = 0; j < 4; j++) {
      int colb = n0 + wn + j * 16 + quad * 4;
      f32x4 bvv = *(const f32x4*)&bias[colb];
      int h = colb >> 6, d0 = colb & 63;
#pragma unroll
      for (int i = 0; i < 4; i++) {
        int s_tok = m0 + wm + i * 16 + c;
        int bb = s_tok >> 10, s = s_tok & 1023;
        u16x4 pk;
#pragma unroll
        for (int r = 0; r < 4; r++) pk[r] = f2bf((acc[i][j][r] + bvv[r]) * sc);
        *(u16x4*)&outB[(size_t)wsel * 4194304 + (((bb * 16 + h) * 1024 + s) * 64) + d0] = pk;
      }
    }
  }
}

// ---------------- Flash attention, 16x16x32 MFMA, streaming softmax ---------
// grid (bh=64, qt=8): all qt blocks of one bh land on one XCD. Register
// prefetch dbuf. PV uses swapped operands -> AO epilogue is packed u16x4
// stores with the lane's own 1/l (no shuffle).
__global__ __launch_bounds__(256) void k_attn(
    const unsigned short* __restrict__ Q, const unsigned short* __restrict__ K,
    const unsigned short* __restrict__ Vt, const float* __restrict__ colbias,
    const int* __restrict__ nearest, unsigned short* __restrict__ AO) {
  __shared__ unsigned short Ks[64 * 72];     // [key][d]
  __shared__ unsigned short Vs[64 * 72];     // [d][key]
  __shared__ unsigned short Ps[4][32 * 72];  // per-wave [q][key]
  __shared__ float Cb[1024];
  int tid = threadIdx.x, wid = tid >> 6, lane = tid & 63;
  int c = lane & 15, quad = lane >> 4;
  int bh = blockIdx.x, qt = blockIdx.y;
  int b = bh >> 4, head = bh & 15;
  int q0 = qt * 128, wq = wid * 32;
  const unsigned short* Qg = Q  + (size_t)(bh * 1024 + q0 + wq) * 64;
  const unsigned short* Kg = K  + (size_t)bh * 1024 * 64;
  const unsigned short* Vg = Vt + (size_t)bh * 64 * 1024;

  *(float4*)&Cb[tid * 4] = *(const float4*)&colbias[b * 1024 + tid * 4];

  s16x8 qf[2][2];
#pragma unroll
  for (int nt = 0; nt < 2; nt++)
#pragma unroll
    for (int ks = 0; ks < 2; ks++)
      qf[nt][ks] = *(const s16x8*)&Qg[(nt * 16 + c) * 64 + ks * 32 + quad * 8];

  int nq[2];
  nq[0] = nearest[b * 1024 + q0 + wq + c];
  nq[1] = nearest[b * 1024 + q0 + wq + 16 + c];

  f32x4 o[2][4];
#pragma unroll
  for (int i = 0; i < 2; i++)
#pragma unroll
    for (int j = 0; j < 4; j++) o[i][j] = (f32x4){0.f, 0.f, 0.f, 0.f};
  float lrun[2] = {0.f, 0.f};

  int srow = tid >> 3, scol8 = (tid & 7) * 8;

  u16x8 kr[2], vr[2];
#pragma unroll
  for (int it = 0; it < 2; ++it) {
    int r2 = it * 32 + srow;
    kr[it] = *(const u16x8*)&Kg[r2 * 64 + scol8];
    vr[it] = *(const u16x8*)&Vg[r2 * 1024 + scol8];
  }
  __syncthreads();   // Cb visible before first use

  for (int kc = 0; kc < 16; ++kc) {
#pragma unroll
    for (int it = 0; it < 2; ++it) {
      int r2 = it * 32 + srow;
      *(u16x8*)&Ks[r2 * 72 + scol8] = kr[it];
      *(u16x8*)&Vs[r2 * 72 + scol8] = vr[it];
    }
    __syncthreads();
    if (kc < 15) {
#pragma unroll
      for (int it = 0; it < 2; ++it) {
        int r2 = it * 32 + srow;
        kr[it] = *(const u16x8*)&Kg[((kc + 1) * 64 + r2) * 64 + scol8];
        vr[it] = *(const u16x8*)&Vg[r2 * 1024 + (kc + 1) * 64 + scol8];
      }
    }

    // S^T = K . Q^T : st[mt][nt] (key = mt*16+quad*4+r, q = nt*16+c)
    f32x4 st[4][2];
#pragma unroll
    for (int mt = 0; mt < 4; mt++)
#pragma unroll
      for (int nt = 0; nt < 2; nt++) st[mt][nt] = (f32x4){0.f, 0.f, 0.f, 0.f};
#pragma unroll
    for (int mt = 0; mt < 4; mt++)
#pragma unroll
      for (int ks = 0; ks < 2; ks++) {
        s16x8 a = *(const s16x8*)&Ks[(mt * 16 + c) * 72 + ks * 32 + quad * 8];
#pragma unroll
        for (int nt = 0; nt < 2; nt++)
          st[mt][nt] = __builtin_amdgcn_mfma_f32_16x16x32_bf16(a, qf[nt][ks], st[mt][nt], 0, 0, 0);
      }

    // bias + exp2 + partial row-sum + pack P -> LDS [q][key]
#pragma unroll
    for (int mt = 0; mt < 4; mt++) {
      f32x4 cb = *(const f32x4*)&Cb[kc * 64 + mt * 16 + quad * 4];
#pragma unroll
      for (int nt = 0; nt < 2; nt++) {
        u16x4 pk;
#pragma unroll
        for (int r = 0; r < 4; r++) {
          int keyg = kc * 64 + mt * 16 + quad * 4 + r;
          float x = st[mt][nt][r] + cb[r] + ((keyg == nq[nt]) ? VERB2 : 0.f);
          float e = EXP2F(x);
          lrun[nt] += e;
          pk[r] = f2bf(e);
        }
        *(u16x4*)&Ps[wid][(nt * 16 + c) * 72 + mt * 16 + quad * 4] = pk;
      }
    }
    __asm__ volatile("s_waitcnt lgkmcnt(0)" ::: "memory");

    // O += (P . V) computed SWAPPED: o[mtq][ntd] rows = d, cols = q
#pragma unroll
    for (int ks = 0; ks < 2; ks++) {
      s16x8 pa[2];
#pragma unroll
      for (int mtq = 0; mtq < 2; mtq++)
        pa[mtq] = *(const s16x8*)&Ps[wid][(mtq * 16 + c) * 72 + ks * 32 + quad * 8];
#pragma unroll
      for (int ntd = 0; ntd < 4; ntd++) {
        s16x8 vb = *(const s16x8*)&Vs[(ntd * 16 + c) * 72 + ks * 32 + quad * 8];
#pragma unroll
        for (int mtq = 0; mtq < 2; mtq++)
          o[mtq][ntd] = __builtin_amdgcn_mfma_f32_16x16x32_bf16(vb, pa[mtq], o[mtq][ntd], 0, 0, 0);
      }
    }
    __syncthreads();
  }

  // l-reduction across quads; lane's own token = mtq*16+c -> no shuffle
#pragma unroll
  for (int nt = 0; nt < 2; nt++) {
    lrun[nt] += __shfl_xor(lrun[nt], 16, 64);
    lrun[nt] += __shfl_xor(lrun[nt], 32, 64);
  }
  float linv[2] = {1.0f / lrun[0], 1.0f / lrun[1]};
#pragma unroll
  for (int mtq = 0; mtq < 2; mtq++) {
    size_t row = (size_t)(b * 1024 + q0 + wq + mtq * 16 + c);
#pragma unroll
    for (int ntd = 0; ntd < 4; ntd++) {
      int d0 = ntd * 16 + quad * 4;
      u16x4 pk;
#pragma unroll
      for (int r = 0; r < 4; r++) pk[r] = f2bf(o[mtq][ntd][r] * linv[mtq]);
      *(u16x4*)&AO[row * 1024 + head * 64 + d0] = pk;
    }
  }
}

// ---------------------------------------------------------------------------
extern "C" void kernel_launch(void* const* d_in, const int* in_sizes, int n_in,
                              void* d_out, int out_size, void* d_ws, size_t ws_size,
                              hipStream_t stream) {
  const float* hs     = (const float*)d_in[0];
  const int*   morpho = (const int*)d_in[1];
  const float* Wq = (const float*)d_in[2];
  const float* bq = (const float*)d_in[3];
  const float* Wk = (const float*)d_in[4];
  const float* bk = (const float*)d_in[5];
  const float* Wv = (const float*)d_in[6];
  const float* bv = (const float*)d_in[7];
  const float* Wo = (const float*)d_in[8];
  const float* bo = (const float*)d_in[9];
  float* out = (float*)d_out;

  char* ws = (char*)d_ws;
  unsigned short* hsb = (unsigned short*)(ws);                    // 8 MB [4096][1024]
  unsigned short* Wt  = (unsigned short*)(ws + (8u << 20));       // 8 MB [4][1024][1024]
  unsigned short* Qb  = (unsigned short*)(ws + (16u << 20));      // Q +16MB, K +24MB
  unsigned short* Kb  = (unsigned short*)(ws + (24u << 20));
  unsigned short* Vtb = (unsigned short*)(ws + (40u << 20));      // 8 MB [B,NH,HD,S]
  float* colbias      = (float*)(ws + (48u << 20));               // 16 KB
  int*   nearestp     = (int*)(ws + (48u << 20) + (16u << 10));   // 16 KB
  unsigned short* AO  = hsb;  // reuse: hs_bf16 dead after QKV GEMM

  k_prep<<<3088, 256, 0, stream>>>(hs, hsb, Wq, Wk, Wv, Wo, Wt, morpho,
                                   colbias, nearestp);
  k_gemm<0><<<dim3(24, 32), 256, 0, stream>>>(hsb, Wt, bq, bk, bv, Qb, Vtb, nullptr);
  k_attn<<<dim3(64, 8), 256, 0, stream>>>(Qb, Kb, Vtb, colbias, nearestp, AO);
  k_gemm<1><<<dim3(8, 32), 256, 0, stream>>>(AO, Wt + 3 * 1048576, bo, nullptr, nullptr,
                                             nullptr, nullptr, out);
  (void)in_sizes; (void)n_in; (void)out_size; (void)ws_size; (void)Kb;
}